// Round 15
// baseline (159.122 us; speedup 1.0000x reference)
//
#include <hip/hip_runtime.h>

namespace {

typedef _Float16 half_t;
typedef _Float16 half2_t __attribute__((ext_vector_type(2)));
typedef _Float16 half4_t __attribute__((ext_vector_type(4)));
typedef _Float16 half8_t __attribute__((ext_vector_type(8)));

constexpr int Wd = 160, Hd = 192, Dd = 160;
constexpr int TX = 16, TY = 16, CZ = 80;
constexpr int HW = Hd * Wd;
constexpr int LIVE = CZ + 8;               // 88 slices per block
constexpr float INV_K = 1.0f / 729.0f;
constexpr float INV_TOT = 1.0f / 9830400.0f;   // 2*160*192*160
constexpr int R8 = 17;     // xs8 row stride in half8 units (16 cols + 1 pad)
constexpr int ROWS = 24;   // exactly the 16+8 y-halo rows needed

// ROUND 25: b128 producer stores on the R22 base (pairing reverted).
// R24 post-mortem: halving barriers HURT (76->81 us) -- with R20 (blocks/
// CU ~flat) and R17 (memory off-path) this triangulates the binding
// resource: the LDS PIPE (~700 cyc/block-slice x 2 blocks/CU ~ saturates
// the 1105-cyc wall; conflict counter bit-identical 5.6448M across R22/
// R23/R24 = xs8 pattern). Store defect found by bank arithmetic: producer
// b32/b16 writes at 16B-aligned slot bases put all 64 lanes at dword
// offsets == delta (mod 4) -> only 8 usable banks -> structural 8-way on
// all 18 store instrs (~300 cyc/slice). Fix: pack each column's
// {II,IT,TT,I,T,0,0,0} in registers and write ONE b128 per column:
// 18 -> 6 store wave-instrs, each lane spanning 4 consecutive banks
// (full 32-bank spread, pure throughput). VALU +~6 pk-cvt/mov (VALU 37%,
// has slack). Consumer/ring/schedule = R22 verbatim.
// INVARIANTS: WRITE_SIZE ~30 KB, FETCH ~42 MB, VGPR ~72-88.
// PREDICT: conflicts 5.64M -> ~1.5-2.5M, profiled 76 -> ~64-70 us.

__global__ __launch_bounds__(256)
void ncc_main(const float* __restrict__ inp, const float* __restrict__ tgt,
              float* __restrict__ out)
{
    __shared__ half8_t xs8[2][ROWS * R8];    // 2 x 6528 B: {II,IT,TT,I,T,-,-,-}
    __shared__ half4_t ringAB[9 * 256];      // 18432 B: z-ring {II,IT,TT,I}
    __shared__ half_t  ringT[9 * 256];       //  4608 B: z-ring {T}
    __shared__ float   red[4];

    const int tid = threadIdx.x;

    // ---- XCD-aware remap (R17): 480 blocks = 8 x 60, bijective.
    const int lin = (int)blockIdx.x + 10 * (int)blockIdx.y + 120 * (int)blockIdx.z;
    const int swz = (lin & 7) * 60 + (lin >> 3);
    const int bx = swz % 10;
    const int by = (swz / 10) % 12;
    const int bz = swz / 120;

    const int n  = bz >> 1;
    const int zc = bz & 1;
    const int x0 = bx * TX, y0 = by * TY, z0 = zc * CZ;

    // zero the ring (all 256 entries per slot; prologue barrier orders it)
    #pragma unroll
    for (int q = 0; q < 9; ++q) {
        ringAB[q * 256 + tid] = (half4_t)0;
        ringT[q * 256 + tid] = (half_t)0.f;
    }

    // ---- producer decode: tid 128..223 -> (row r 0..23) x (h,q col-group)
    const bool isProd = (tid >= 128) && (tid < 224);
    const int up = (tid >= 128) ? (tid - 128) : 0;
    const int r  = (up < 96) ? (up >> 2) : 0;
    const int hq = up & 3;
    const int h  = hq >> 1, qx = hq & 1;
    const int gy = y0 - 4 + r;
    const bool yok = (gy >= 0) && (gy < Hd);
    const int gyc = min(max(gy, 0), Hd - 1);
    const int gxs = x0 - 4 + 8 * h + 4 * qx;   // 12 input cols gxs..gxs+11

#define DECODE(c) \
    int voff##c; float m##c; \
    { const int gx = gxs + 4 * (c); \
      m##c = (yok && gx >= 0 && gx < Wd) ? 1.f : 0.f; \
      const int gxc = min(max(gx, 0), Wd - 4); \
      voff##c = gyc * Wd + gxc; }
    DECODE(0) DECODE(1) DECODE(2)
#undef DECODE

    const int nb = n * (Dd * HW);            // < 2^24, int math is exact
    const float* baseI = inp + nb;           // uniform -> SGPR pair
    const float* baseT = tgt + nb;

    // producer store bases: output cols col0..col0+3, half8 layout
    const int col0 = 8 * h + 4 * qx;
    half_t* const sb0 = (half_t*)xs8[0] + (r * R8 + col0) * 8;
    half_t* const sb1 = (half_t*)xs8[1] + (r * R8 + col0) * 8;

    // ---- consumer decode: tid<128 owns output pair (xi, 2yp),(xi, 2yp+1)
    const int xi = tid & 15;
    const int yp = (tid >> 4) & 7;
    const bool p2on = tid < 128;
    const half8_t* const rd8_0 = &xs8[0][(2 * yp) * R8 + xi];
    const half8_t* const rd8_1 = &xs8[1][(2 * yp) * R8 + xi];

    float4 S4a = make_float4(0.f, 0.f, 0.f, 0.f);
    float4 S4b = make_float4(0.f, 0.f, 0.f, 0.f);
    float STa = 0.f, STb = 0.f, acc = 0.f;

    // single producer prefetch set (depth-1; loads are L2-resident per R17)
    float4 SI0, SI1, SI2, ST0, ST1, ST2;
    SI0 = SI1 = SI2 = ST0 = ST1 = ST2 = make_float4(0.f, 0.f, 0.f, 0.f);

#define PRELOAD(zz) { \
    const float* pI = baseI + (zz) * HW; \
    const float* pT = baseT + (zz) * HW; \
    SI0 = *(const float4*)(pI + voff0); ST0 = *(const float4*)(pT + voff0); \
    SI1 = *(const float4*)(pI + voff1); ST1 = *(const float4*)(pT + voff1); \
    SI2 = *(const float4*)(pI + voff2); ST2 = *(const float4*)(pT + voff2); }

#define F4E(v, e) ((e) == 0 ? (v).x : ((e) == 1 ? (v).y : ((e) == 2 ? (v).z : (v).w)))

    // 9-tap sliding windows (4 outputs from 12 inputs), same fold as before
#define WIN4(PP, W) { \
    float ss = PP[0] + PP[1] + PP[2] + PP[3] + PP[4] + PP[5] + PP[6] + PP[7] + PP[8]; \
    W[0] = ss; ss += PP[9]  - PP[0]; W[1] = ss; \
               ss += PP[10] - PP[1]; W[2] = ss; \
               ss += PP[11] - PP[2]; W[3] = ss; }

    // compute + store one slice's x-windows (all 5 fields) to SBP.
    // Store = ONE b128 per output column (packed half8 slot).
#define PRODUCE(SBP) { \
    float Im[12], Tr[12], p[12]; \
    float wII[4], wIT[4], wTT[4], wI[4], wT[4]; \
    _Pragma("unroll") \
    for (int e = 0; e < 4; ++e) { \
        Im[e]     = F4E(SI0, e) * m0;  Tr[e]     = fmaf(F4E(ST0, e), 0.5f, 0.5f); \
        Im[4 + e] = F4E(SI1, e) * m1;  Tr[4 + e] = fmaf(F4E(ST1, e), 0.5f, 0.5f); \
        Im[8 + e] = F4E(SI2, e) * m2;  Tr[8 + e] = fmaf(F4E(ST2, e), 0.5f, 0.5f); } \
    _Pragma("unroll") \
    for (int i = 0; i < 12; ++i) \
        p[i] = Im[i] * F4E((i < 4 ? SI0 : (i < 8 ? SI1 : SI2)), i & 3); \
    WIN4(p, wII) \
    _Pragma("unroll") \
    for (int i = 0; i < 12; ++i) p[i] = Im[i] * Tr[i]; \
    WIN4(p, wIT) \
    WIN4(Im, wI) \
    _Pragma("unroll") \
    for (int i = 0; i < 12; ++i) Im[i] = Tr[i] * (i < 4 ? m0 : (i < 8 ? m1 : m2)); \
    _Pragma("unroll") \
    for (int i = 0; i < 12; ++i) p[i] = Im[i] * Tr[i]; \
    WIN4(p, wTT) \
    WIN4(Im, wT) \
    _Pragma("unroll") \
    for (int cc = 0; cc < 4; ++cc) { \
        const half8_t slot = {(half_t)wII[cc], (half_t)wIT[cc], \
                              (half_t)wTT[cc], (half_t)wI[cc], \
                              (half_t)wT[cc], (half_t)0.f, \
                              (half_t)0.f, (half_t)0.f}; \
        *(half8_t*)((SBP) + cc * 8) = slot; } }

    // ---- prologue: produce slice 0 into buf0; preload slice 1
    if (isProd) {
        if (z0 - 4 >= 0) { PRELOAD(z0 - 4) PRODUCE(sb0) }
        if (z0 - 3 >= 0) PRELOAD(z0 - 3)
    }
    __syncthreads();

    // one step: producer makes slice k+1, consumer eats slice k; 1 barrier
#define STEP_BODY(UU) { \
    const int k = tb + (UU); \
    if (isProd) { \
        const int zi1 = z0 - 3 + k;             /* z of slice k+1 */ \
        if ((k + 1) < LIVE && zi1 >= 0 && zi1 < Dd) { \
            if (((UU) & 1) == 0) PRODUCE(sb1) else PRODUCE(sb0) \
        } \
        const int zi2 = z0 - 2 + k;             /* z of slice k+2 */ \
        if ((k + 2) < LIVE && zi2 >= 0 && zi2 < Dd) PRELOAD(zi2) \
    } \
    { /* consumer: slice k from buf[k&1] */ \
        const int zi = z0 - 4 + k; \
        const bool zok = (zi >= 0) && (zi < Dd); \
        half2_t a01_0 = (half2_t)0, a23_0 = (half2_t)0; \
        half2_t a01_1 = (half2_t)0, a23_1 = (half2_t)0; \
        half_t aT0 = (half_t)0.f, aT1 = (half_t)0.f; \
        if (zok && p2on) { \
            const half8_t* const rd8 = (((UU) & 1) != 0) ? rd8_1 : rd8_0; \
            const half8_t w0 = rd8[0]; \
            const half8_t w9 = rd8[9 * R8]; \
            half2_t m01 = (half2_t)0, m23 = (half2_t)0, m4 = (half2_t)0; \
            _Pragma("unroll") \
            for (int kk = 1; kk < 9; ++kk) { \
                const half8_t w = rd8[kk * R8]; \
                const half2_t* wp = (const half2_t*)&w; \
                m01 += wp[0]; m23 += wp[1]; m4 += wp[2]; \
            } \
            const half2_t* w0p = (const half2_t*)&w0; \
            const half2_t* w9p = (const half2_t*)&w9; \
            a01_0 = m01 + w0p[0]; a23_0 = m23 + w0p[1]; aT0 = m4.x + w0p[2].x; \
            a01_1 = m01 + w9p[0]; a23_1 = m23 + w9p[1]; aT1 = m4.x + w9p[2].x; \
        } \
        if (p2on) { \
            const int sl = (UU) % 9;            /* static */ \
            half8_t* const rAB8 = (half8_t*)&ringAB[sl * 256 + 2 * tid]; \
            half2_t* const rT  = (half2_t*)&ringT[sl * 256 + 2 * tid]; \
            const half8_t oA = *rAB8; \
            const half2_t oT = *rT; \
            S4a.x += (float)a01_0.x - (float)oA[0]; \
            S4a.y += (float)a01_0.y - (float)oA[1]; \
            S4a.z += (float)a23_0.x - (float)oA[2]; \
            S4a.w += (float)a23_0.y - (float)oA[3]; \
            STa   += (float)aT0 - (float)oT.x; \
            S4b.x += (float)a01_1.x - (float)oA[4]; \
            S4b.y += (float)a01_1.y - (float)oA[5]; \
            S4b.z += (float)a23_1.x - (float)oA[6]; \
            S4b.w += (float)a23_1.y - (float)oA[7]; \
            STb   += (float)aT1 - (float)oT.y; \
            const half8_t nA = {a01_0.x, a01_0.y, a23_0.x, a23_0.y, \
                                a01_1.x, a01_1.y, a23_1.x, a23_1.y}; \
            *rAB8 = nA; \
            const half2_t nT = {aT0, aT1}; \
            *rT = nT; \
        } \
        if (k >= 8 && p2on) {                   /* output z = z0+k-8 */ \
            { const float sii = S4a.x, sit = S4a.y, stt = S4a.z, si = S4a.w, stv = STa; \
              const float cross = sit - si * stv * INV_K; \
              const float tvar  = stt - stv * stv * INV_K; \
              const float ivar  = sii - si  * si  * INV_K; \
              acc += cross * cross * __builtin_amdgcn_rcpf(tvar * ivar + 1e-5f); } \
            { const float sii = S4b.x, sit = S4b.y, stt = S4b.z, si = S4b.w, stv = STb; \
              const float cross = sit - si * stv * INV_K; \
              const float tvar  = stt - stv * stv * INV_K; \
              const float ivar  = sii - si  * si  * INV_K; \
              acc += cross * cross * __builtin_amdgcn_rcpf(tvar * ivar + 1e-5f); } \
        } \
    } \
    __syncthreads(); }

    for (int tb = 0; tb < 90; tb += 18) {          // 88 live; 18-unroll x 5
        #pragma unroll
        for (int uu = 0; uu < 18; ++uu) {
            if (tb + uu < LIVE) STEP_BODY(uu)
        }
    }
#undef STEP_BODY
#undef PRODUCE
#undef WIN4
#undef F4E
#undef PRELOAD

    // ---- block reduction + fused finalize (one atomic per block)
    #pragma unroll
    for (int off = 32; off > 0; off >>= 1) acc += __shfl_down(acc, off, 64);
    if ((tid & 63) == 0) red[tid >> 6] = acc;
    __syncthreads();
    if (tid == 0) {
        const float tot = red[0] + red[1] + red[2] + red[3];
        atomicAdd(out, -tot * INV_TOT);
    }
}

} // namespace

extern "C" void kernel_launch(void* const* d_in, const int* in_sizes, int n_in,
                              void* d_out, int out_size, void* d_ws, size_t ws_size,
                              hipStream_t stream)
{
    const float* inp = (const float*)d_in[0];
    const float* tgt = (const float*)d_in[1];
    float* out = (float*)d_out;

    hipMemsetAsync(d_out, 0, sizeof(float), stream);   // d_out re-poisoned each call
    dim3 grid(Wd / TX, Hd / TY, 2 * (Dd / CZ));        // (10,12,4) = 480 blocks
    ncc_main<<<grid, 256, 0, stream>>>(inp, tgt, out);
}